// Round 2
// baseline (140.491 us; speedup 1.0000x reference)
//
#include <hip/hip_runtime.h>
#include <hip/hip_bf16.h>

#define N 8192
#define F 128

typedef __attribute__((ext_vector_type(4)))  float f32x4;
typedef __attribute__((ext_vector_type(16))) float f32x16;
typedef __attribute__((ext_vector_type(8)))  short short8;

static __device__ __forceinline__ short bf16bits(float x) {
  __hip_bfloat16 b = __float2bfloat16(x);   // RNE, compiler uses native cvt
  return *reinterpret_cast<short*>(&b);
}

// ---------------------------------------------------------------------------
// Kernel A: Wh = h @ W (fp32), fused c[i] = Wh[i].a2 + p.a3, d[i] = Wh[i].a1 - p.a3,
// and WhT (bf16, [128][8192]) for the flash kernel's B operand.
// 512 blocks x 256 threads, 16 rows/block, 2 blocks/CU (W staged in 64 KiB LDS).
// ---------------------------------------------------------------------------
__global__ __launch_bounds__(256) void k_gemm_cd(
    const float* __restrict__ h, const float* __restrict__ pos,
    const float* __restrict__ W, const float* __restrict__ a,
    unsigned short* __restrict__ WhT, float* __restrict__ cArr,
    float* __restrict__ dArr)
{
  __shared__ float Ws[128 * 128];          // 64 KiB, reused as transpose buffer after
  const int tid = threadIdx.x;
  const int r0  = blockIdx.x * 16;

  // stage W (coalesced float4)
  {
    f32x4* Ws4 = (f32x4*)Ws;
    const f32x4* Wg4 = (const f32x4*)W;
#pragma unroll
    for (int q = 0; q < 16; ++q) Ws4[q * 256 + tid] = Wg4[q * 256 + tid];
  }
  __syncthreads();

  const int rg  = tid >> 5;    // 0..7 -> rows rg*2, rg*2+1
  const int c32 = tid & 31;    // cols c32*4 .. c32*4+3

  f32x4 acc0, acc1;
#pragma unroll
  for (int i = 0; i < 4; ++i) { acc0[i] = 0.0f; acc1[i] = 0.0f; }

  const f32x4* h40 = (const f32x4*)(h + (size_t)(r0 + rg * 2) * 128);
  const f32x4* h41 = (const f32x4*)(h + (size_t)(r0 + rg * 2 + 1) * 128);
  const f32x4* Ws4 = (const f32x4*)Ws;

#pragma unroll 4
  for (int k4 = 0; k4 < 32; ++k4) {
    f32x4 hv0 = h40[k4];
    f32x4 hv1 = h41[k4];
#pragma unroll
    for (int e = 0; e < 4; ++e) {
      f32x4 w = Ws4[(k4 * 4 + e) * 32 + c32];
      acc0 += hv0[e] * w;
      acc1 += hv1[e] * w;
    }
  }

  // fused row dots: s1 = Wh.a1 (for d), s2 = Wh.a2 (for c)
  f32x4 a1v = *(const f32x4*)(a + c32 * 4);
  f32x4 a2v = *(const f32x4*)(a + 128 + c32 * 4);
#pragma unroll
  for (int rr = 0; rr < 2; ++rr) {
    f32x4 accR = rr ? acc1 : acc0;
    f32x4 t1 = accR * a1v;
    f32x4 t2 = accR * a2v;
    float s1 = t1[0] + t1[1] + t1[2] + t1[3];
    float s2 = t2[0] + t2[1] + t2[2] + t2[3];
#pragma unroll
    for (int m = 1; m < 32; m <<= 1) {
      s1 += __shfl_xor(s1, m);
      s2 += __shfl_xor(s2, m);
    }
    if (c32 == 0) {
      const int row = r0 + rg * 2 + rr;
      float pa = pos[row * 3 + 0] * a[256] + pos[row * 3 + 1] * a[257] +
                 pos[row * 3 + 2] * a[258];
      cArr[row] = s2 + pa;     // i-side
      dArr[row] = s1 - pa;     // j-side
    }
  }

  // transpose via LDS (reuse Ws), write bf16 WhT[col][row]
  __syncthreads();
  float* tmp = Ws;             // [16][132] padded
  {
    const int base = (rg * 2) * 132 + c32 * 4;
    *(f32x4*)&tmp[base]       = acc0;
    *(f32x4*)&tmp[base + 132] = acc1;
  }
  __syncthreads();
  {
    const int col  = tid >> 1;         // 0..127
    const int half = tid & 1;          // rows half*8 .. half*8+7
    short8 o;
#pragma unroll
    for (int rr = 0; rr < 8; ++rr)
      o[rr] = bf16bits(tmp[(half * 8 + rr) * 132 + col]);
    *(short8*)(WhT + (size_t)col * N + r0 + half * 8) = o;
  }
}

// ---------------------------------------------------------------------------
// Kernel B: flash-style attention (scores bounded -> no max subtraction).
// Grid 128*JC: bid = (rowblock<<jcShift) | jc.  64 rows x (N/JC) j per block.
// 4 waves: (w&1) selects 32-row tile, (w>>1) selects j-half of the chunk.
// A-frag = P computed in-register; B-frag = contiguous short8 from WhT (L2).
// Dynamic LDS: dS[jSlice] + red[64*128] + denred[64].
// ---------------------------------------------------------------------------
__global__ __launch_bounds__(256, 4) void k_flash(
    const unsigned short* __restrict__ WhT, const float* __restrict__ cArr,
    const float* __restrict__ dArr, float* __restrict__ pnum,
    float* __restrict__ pden, int jcShift)
{
  extern __shared__ float smem[];
  const int JC     = 1 << jcShift;
  const int jSlice = N >> jcShift;

  float* dS     = smem;                    // jSlice floats
  float* red    = smem + jSlice;           // 64*128 floats
  float* denred = red + 64 * 128;          // 64 floats

  const int tid = threadIdx.x;
  const int bid = blockIdx.x;
  const int jc  = bid & (JC - 1);
  const int r0  = (bid >> jcShift) * 64;

  // stage this block's d-slice
  {
    const f32x4* s4 = (const f32x4*)(dArr + (size_t)jc * jSlice);
    f32x4* t4 = (f32x4*)dS;
    const int nq = jSlice >> 10;           // (jSlice/4)/256
    for (int q = 0; q < nq; ++q) t4[q * 256 + tid] = s4[q * 256 + tid];
  }
  __syncthreads();

  const int w  = tid >> 6;
  const int l  = tid & 63;
  const int cl = l & 31;
  const int rowl = 32 * (w & 1) + cl;      // A-frag row = lane&31
  const int jw = (w >> 1) * (jSlice >> 1);
  const int kb = (l >> 5) * 8;             // A/B-frag k base

  const float L2E = 1.44269504f;
  const float ciL = cArr[r0 + rowl] * L2E;

  f32x16 acc0, acc1, acc2, acc3;
#pragma unroll
  for (int i = 0; i < 16; ++i) { acc0[i] = 0; acc1[i] = 0; acc2[i] = 0; acc3[i] = 0; }
  float den = 0.0f;

  const unsigned short* v0 = WhT + (size_t)(cl +  0) * N + (size_t)jc * jSlice;
  const unsigned short* v1 = WhT + (size_t)(cl + 32) * N + (size_t)jc * jSlice;
  const unsigned short* v2 = WhT + (size_t)(cl + 64) * N + (size_t)jc * jSlice;
  const unsigned short* v3 = WhT + (size_t)(cl + 96) * N + (size_t)jc * jSlice;

  const int iters = jSlice >> 5;           // (jSlice/2)/16 per wave

  // prologue: first B-frags
  short8 b0 = *(const short8*)(v0 + jw + kb);
  short8 b1 = *(const short8*)(v1 + jw + kb);
  short8 b2 = *(const short8*)(v2 + jw + kb);
  short8 b3 = *(const short8*)(v3 + jw + kb);

  for (int kk = 0; kk < iters; ++kk) {
    const int jo = jw + kk * 16 + kb;
    f32x4 dj0 = *(const f32x4*)&dS[jo];
    f32x4 dj1 = *(const f32x4*)&dS[jo + 4];
    float p[8];
#pragma unroll
    for (int e = 0; e < 8; ++e) {
      float dj = (e < 4) ? dj0[e] : dj1[e - 4];
      float u = __builtin_fmaf(dj, L2E, ciL);  // (c_i + d_j) * log2(e)
      u = fmaxf(u, 0.2f * u);                  // leaky_relu (log2 domain, slope>0)
      float pv = __builtin_amdgcn_exp2f(u);
      den += pv;
      p[e] = pv;
    }
    short8 af;
#pragma unroll
    for (int e = 0; e < 8; ++e) af[e] = bf16bits(p[e]);

    // prefetch next iteration's B-frags (last-iter overrun stays inside d_ws)
    const int jn = jo + 16;
    short8 n0 = *(const short8*)(v0 + jn);
    short8 n1 = *(const short8*)(v1 + jn);
    short8 n2 = *(const short8*)(v2 + jn);
    short8 n3 = *(const short8*)(v3 + jn);

    acc0 = __builtin_amdgcn_mfma_f32_32x32x16_bf16(af, b0, acc0, 0, 0, 0);
    acc1 = __builtin_amdgcn_mfma_f32_32x32x16_bf16(af, b1, acc1, 0, 0, 0);
    acc2 = __builtin_amdgcn_mfma_f32_32x32x16_bf16(af, b2, acc2, 0, 0, 0);
    acc3 = __builtin_amdgcn_mfma_f32_32x32x16_bf16(af, b3, acc3, 0, 0, 0);
    b0 = n0; b1 = n1; b2 = n2; b3 = n3;
  }

  // full row denominator: lanes l and l+32 hold the two k-halves of the same row
  den += __shfl_xor(den, 32);

  // cross-wave reduce (j-halves) through LDS
  const int rtb = 32 * (w & 1);
  const int rhi = 4 * (l >> 5);
  if (w < 2) {
#pragma unroll
    for (int reg = 0; reg < 16; ++reg) {
      const int rt = (reg & 3) + 8 * (reg >> 2) + rhi;
      red[(rtb + rt) * 128 +  0 + cl] = acc0[reg];
      red[(rtb + rt) * 128 + 32 + cl] = acc1[reg];
      red[(rtb + rt) * 128 + 64 + cl] = acc2[reg];
      red[(rtb + rt) * 128 + 96 + cl] = acc3[reg];
    }
    if (l < 32) denred[rtb + l] = den;
  }
  __syncthreads();
  if (w >= 2) {
#pragma unroll
    for (int reg = 0; reg < 16; ++reg) {
      const int rt = (reg & 3) + 8 * (reg >> 2) + rhi;
      red[(rtb + rt) * 128 +  0 + cl] += acc0[reg];
      red[(rtb + rt) * 128 + 32 + cl] += acc1[reg];
      red[(rtb + rt) * 128 + 64 + cl] += acc2[reg];
      red[(rtb + rt) * 128 + 96 + cl] += acc3[reg];
    }
    if (l < 32) denred[rtb + l] += den;
  }
  __syncthreads();

  // write partials
  {
    f32x4* pn4 = (f32x4*)(pnum + (size_t)jc * N * F + (size_t)r0 * 128);
    const f32x4* r4 = (const f32x4*)red;
#pragma unroll
    for (int q = 0; q < 8; ++q) pn4[q * 256 + tid] = r4[q * 256 + tid];
    if (tid < 64) pden[(size_t)jc * N + r0 + tid] = denred[tid];
  }
}

// ---------------------------------------------------------------------------
// Kernel C: combine the JC j-chunk partials, normalize, ELU, store fp32.
// ---------------------------------------------------------------------------
__global__ __launch_bounds__(256) void k_final(
    const float* __restrict__ pnum, const float* __restrict__ pden,
    float* __restrict__ out, int JC)
{
  const int g = blockIdx.x * 256 + threadIdx.x;       // float4 index
  const int row = g >> 5;
  f32x4 n;
#pragma unroll
  for (int i = 0; i < 4; ++i) n[i] = 0.0f;
  float dd = 0.0f;
  for (int c = 0; c < JC; ++c) {
    n += ((const f32x4*)pnum)[(size_t)c * (N * F / 4) + g];
    dd += pden[(size_t)c * N + row];
  }
  f32x4 r = n * (1.0f / dd);
#pragma unroll
  for (int i = 0; i < 4; ++i) {
    float x = r[i];
    r[i] = x > 0.0f ? x : (__builtin_amdgcn_exp2f(x * 1.44269504f) - 1.0f);
  }
  ((f32x4*)out)[g] = r;
}

extern "C" void kernel_launch(void* const* d_in, const int* in_sizes, int n_in,
                              void* d_out, int out_size, void* d_ws, size_t ws_size,
                              hipStream_t stream)
{
  const float* h   = (const float*)d_in[0];
  const float* pos = (const float*)d_in[1];
  const float* W   = (const float*)d_in[2];
  const float* a   = (const float*)d_in[3];
  float* out = (float*)d_out;

  // choose j-chunk count from available workspace
  int jcShift = 3;
  for (; jcShift > 1; --jcShift) {
    int jc = 1 << jcShift;
    size_t need = (size_t)2 * 1024 * 1024            // WhT bf16
                + (size_t)2 * N * 4                  // cArr, dArr
                + (size_t)jc * N * 4                 // pden
                + (size_t)jc * N * F * 4;            // pnum
    if (need <= ws_size) break;
  }
  const int JC = 1 << jcShift;

  char* ws = (char*)d_ws;
  unsigned short* WhT = (unsigned short*)ws;                 // 2 MiB  bf16 [128][8192]
  float* cArr = (float*)(ws + (size_t)2 * 1024 * 1024);
  float* dArr = cArr + N;
  float* pden = dArr + N;                                    // JC*N floats
  float* pnum = pden + (size_t)JC * N;                       // JC*N*F floats

  const int jSlice = N >> jcShift;
  const size_t dynLds = (size_t)jSlice * 4 + 64 * 128 * 4 + 64 * 4;

  hipLaunchKernelGGL(k_gemm_cd, dim3(512), dim3(256), 0, stream,
                     h, pos, W, a, WhT, cArr, dArr);
  hipLaunchKernelGGL(k_flash, dim3(128 << jcShift), dim3(256), dynLds, stream,
                     WhT, cArr, dArr, pnum, pden, jcShift);
  hipLaunchKernelGGL(k_final, dim3((N * F / 4) / 256), dim3(256), 0, stream,
                     pnum, pden, out, JC);
}

// Round 3
// 115.344 us; speedup vs baseline: 1.2180x; 1.2180x over previous
//
#include <hip/hip_runtime.h>
#include <hip/hip_bf16.h>

#define N 8192
#define F 128
#define JC 4
#define JSLICE (N / JC)          // 2048

typedef __attribute__((ext_vector_type(4)))  float f32x4;
typedef __attribute__((ext_vector_type(16))) float f32x16;
typedef __attribute__((ext_vector_type(8)))  short short8;

static __device__ __forceinline__ short bf16bits(float x) {
  __hip_bfloat16 b = __float2bfloat16(x);   // RNE, native cvt
  return *reinterpret_cast<short*>(&b);
}

// ---------------------------------------------------------------------------
// Kernel A: Wh = h @ W (fp32), fused c[i] = Wh[i].a2 + p.a3, d[i] = Wh[i].a1 - p.a3,
// plus WhTf: fragment-tiled bf16 layout WhTf[(j/16)][col][j%16] (2048 shorts per
// 16-j block) so k_flash's B-frag loads are fully coalesced.
// 512 blocks x 256 threads, 16 rows/block (W staged in 64 KiB LDS).
// ---------------------------------------------------------------------------
__global__ __launch_bounds__(256) void k_gemm_cd(
    const float* __restrict__ h, const float* __restrict__ pos,
    const float* __restrict__ W, const float* __restrict__ a,
    unsigned short* __restrict__ WhTf, float* __restrict__ cArr,
    float* __restrict__ dArr)
{
  __shared__ float Ws[128 * 128];          // 64 KiB, reused as transpose buffer
  const int tid = threadIdx.x;
  const int r0  = blockIdx.x * 16;

  {
    f32x4* Ws4 = (f32x4*)Ws;
    const f32x4* Wg4 = (const f32x4*)W;
#pragma unroll
    for (int q = 0; q < 16; ++q) Ws4[q * 256 + tid] = Wg4[q * 256 + tid];
  }
  __syncthreads();

  const int rg  = tid >> 5;    // 0..7 -> rows rg*2, rg*2+1
  const int c32 = tid & 31;    // cols c32*4 .. c32*4+3

  f32x4 acc0, acc1;
#pragma unroll
  for (int i = 0; i < 4; ++i) { acc0[i] = 0.0f; acc1[i] = 0.0f; }

  const f32x4* h40 = (const f32x4*)(h + (size_t)(r0 + rg * 2) * 128);
  const f32x4* h41 = (const f32x4*)(h + (size_t)(r0 + rg * 2 + 1) * 128);
  const f32x4* Ws4 = (const f32x4*)Ws;

#pragma unroll 4
  for (int k4 = 0; k4 < 32; ++k4) {
    f32x4 hv0 = h40[k4];
    f32x4 hv1 = h41[k4];
#pragma unroll
    for (int e = 0; e < 4; ++e) {
      f32x4 w = Ws4[(k4 * 4 + e) * 32 + c32];
      acc0 += hv0[e] * w;
      acc1 += hv1[e] * w;
    }
  }

  // fused row dots: s1 = Wh.a1 (j-side), s2 = Wh.a2 (i-side)
  f32x4 a1v = *(const f32x4*)(a + c32 * 4);
  f32x4 a2v = *(const f32x4*)(a + 128 + c32 * 4);
#pragma unroll
  for (int rr = 0; rr < 2; ++rr) {
    f32x4 accR = rr ? acc1 : acc0;
    f32x4 t1 = accR * a1v;
    f32x4 t2 = accR * a2v;
    float s1 = t1[0] + t1[1] + t1[2] + t1[3];
    float s2 = t2[0] + t2[1] + t2[2] + t2[3];
#pragma unroll
    for (int m = 1; m < 32; m <<= 1) {
      s1 += __shfl_xor(s1, m);
      s2 += __shfl_xor(s2, m);
    }
    if (c32 == 0) {
      const int row = r0 + rg * 2 + rr;
      float pa = pos[row * 3 + 0] * a[256] + pos[row * 3 + 1] * a[257] +
                 pos[row * 3 + 2] * a[258];
      cArr[row] = s2 + pa;
      dArr[row] = s1 - pa;
    }
  }

  // transpose via LDS (reuse Ws), write bf16 fragment-tiled WhTf
  __syncthreads();
  float* tmp = Ws;             // [16][132] padded
  {
    const int base = (rg * 2) * 132 + c32 * 4;
    *(f32x4*)&tmp[base]       = acc0;
    *(f32x4*)&tmp[base + 132] = acc1;
  }
  __syncthreads();
  {
    const int col  = tid >> 1;         // 0..127
    const int half = tid & 1;          // local rows half*8 .. half*8+7
    short8 o;
#pragma unroll
    for (int rr = 0; rr < 8; ++rr)
      o[rr] = bf16bits(tmp[(half * 8 + rr) * 132 + col]);
    // j = r0 + half*8 + rr ; offset = (j>>4)*2048 + col*16 + (j&15)
    *(short8*)(WhTf + (size_t)(r0 >> 4) * 2048 + col * 16 + half * 8) = o;
  }
}

// ---------------------------------------------------------------------------
// Kernel B: flash attention, scores bounded -> plain partial sums.
// Grid 512: jc = bid>>7 (j-chunk of 2048), rowblock = bid&127 (64 rows).
// 4 waves, each wave covers ALL 64 rows over a 512-j quarter:
//   per iter (16 j): 16 exps/lane -> 2 A-frags, 4 coalesced 1KB B-loads, 8 MFMAs.
// Cross-wave reduce via two 32 KiB LDS buffers (2 store + 2 add waves).
// ---------------------------------------------------------------------------
__global__ __launch_bounds__(256, 2) void k_flash(
    const unsigned short* __restrict__ WhTf, const float* __restrict__ cArr,
    const float* __restrict__ dArr, float* __restrict__ pnum,
    float* __restrict__ pden)
{
  __shared__ __align__(16) float dS[JSLICE];
  __shared__ float redA[64 * 128];
  __shared__ float redB[64 * 128];
  __shared__ float denA[64];
  __shared__ float denB[64];

  const int tid = threadIdx.x;
  const int jc  = blockIdx.x >> 7;
  const int r0  = (blockIdx.x & 127) * 64;

  {
    const f32x4* s4 = (const f32x4*)(dArr + (size_t)jc * JSLICE);
    f32x4* t4 = (f32x4*)dS;
    t4[tid]       = s4[tid];
    t4[256 + tid] = s4[256 + tid];
  }
  __syncthreads();

  const int w  = tid >> 6;
  const int l  = tid & 63;
  const int cl = l & 31;
  const int kh = l >> 5;
  const int jw = w * (JSLICE / 4);          // 512 j per wave
  const float L2E = 1.44269504f;
  const float ci0 = cArr[r0 + cl] * L2E;
  const float ci1 = cArr[r0 + 32 + cl] * L2E;

  f32x16 acc[2][4];
#pragma unroll
  for (int R = 0; R < 2; ++R)
#pragma unroll
    for (int G = 0; G < 4; ++G)
#pragma unroll
      for (int i = 0; i < 16; ++i) acc[R][G][i] = 0.0f;

  float den0 = 0.0f, den1 = 0.0f;

  const unsigned short* bPtr =
      WhTf + ((size_t)(jc * JSLICE + jw) >> 4) * 2048 + cl * 16 + kh * 8;
  const float* dPtr = dS + jw + kh * 8;

  // prologue: first fragments
  short8 b0 = *(const short8*)(bPtr);
  short8 b1 = *(const short8*)(bPtr + 512);
  short8 b2 = *(const short8*)(bPtr + 1024);
  short8 b3 = *(const short8*)(bPtr + 1536);
  f32x4 dj0 = *(const f32x4*)(dPtr);
  f32x4 dj1 = *(const f32x4*)(dPtr + 4);
  bPtr += 2048; dPtr += 16;

  const int iters = (JSLICE / 4) / 16;      // 32
  for (int kk = 0; kk < iters; ++kk) {
    // prefetch next iteration (last-iter overrun stays inside d_ws / LDS block)
    short8 n0 = *(const short8*)(bPtr);
    short8 n1 = *(const short8*)(bPtr + 512);
    short8 n2 = *(const short8*)(bPtr + 1024);
    short8 n3 = *(const short8*)(bPtr + 1536);
    f32x4 nd0 = *(const f32x4*)(dPtr);
    f32x4 nd1 = *(const f32x4*)(dPtr + 4);

    float p0[8], p1[8];
#pragma unroll
    for (int e = 0; e < 8; ++e) {
      float dj = (e < 4) ? dj0[e] : dj1[e - 4];
      float u0 = __builtin_fmaf(dj, L2E, ci0);
      u0 = fmaxf(u0, 0.2f * u0);              // leaky_relu in log2 domain
      float pv0 = __builtin_amdgcn_exp2f(u0);
      den0 += pv0; p0[e] = pv0;
      float u1 = __builtin_fmaf(dj, L2E, ci1);
      u1 = fmaxf(u1, 0.2f * u1);
      float pv1 = __builtin_amdgcn_exp2f(u1);
      den1 += pv1; p1[e] = pv1;
    }
    short8 af0, af1;
#pragma unroll
    for (int e = 0; e < 8; ++e) { af0[e] = bf16bits(p0[e]); af1[e] = bf16bits(p1[e]); }

    acc[0][0] = __builtin_amdgcn_mfma_f32_32x32x16_bf16(af0, b0, acc[0][0], 0, 0, 0);
    acc[1][0] = __builtin_amdgcn_mfma_f32_32x32x16_bf16(af1, b0, acc[1][0], 0, 0, 0);
    acc[0][1] = __builtin_amdgcn_mfma_f32_32x32x16_bf16(af0, b1, acc[0][1], 0, 0, 0);
    acc[1][1] = __builtin_amdgcn_mfma_f32_32x32x16_bf16(af1, b1, acc[1][1], 0, 0, 0);
    acc[0][2] = __builtin_amdgcn_mfma_f32_32x32x16_bf16(af0, b2, acc[0][2], 0, 0, 0);
    acc[1][2] = __builtin_amdgcn_mfma_f32_32x32x16_bf16(af1, b2, acc[1][2], 0, 0, 0);
    acc[0][3] = __builtin_amdgcn_mfma_f32_32x32x16_bf16(af0, b3, acc[0][3], 0, 0, 0);
    acc[1][3] = __builtin_amdgcn_mfma_f32_32x32x16_bf16(af1, b3, acc[1][3], 0, 0, 0);

    b0 = n0; b1 = n1; b2 = n2; b3 = n3;
    dj0 = nd0; dj1 = nd1;
    bPtr += 2048; dPtr += 16;
  }

  // combine kh halves of each row's denominator
  den0 += __shfl_xor(den0, 32);
  den1 += __shfl_xor(den1, 32);

  // cross-wave reduce: waves 0/1 store to A/B, waves 2/3 add to A/B
  float* redW = (w & 1) ? redB : redA;
  float* denW = (w & 1) ? denB : denA;
  const int rhi = 4 * kh;
  if (w < 2) {
#pragma unroll
    for (int reg = 0; reg < 16; ++reg) {
      const int rt = (reg & 3) + 8 * (reg >> 2) + rhi;
#pragma unroll
      for (int R = 0; R < 2; ++R)
#pragma unroll
        for (int G = 0; G < 4; ++G)
          redW[(R * 32 + rt) * 128 + G * 32 + cl] = acc[R][G][reg];
    }
    if (l < 32) { denW[cl] = den0; denW[32 + cl] = den1; }
  }
  __syncthreads();
  if (w >= 2) {
#pragma unroll
    for (int reg = 0; reg < 16; ++reg) {
      const int rt = (reg & 3) + 8 * (reg >> 2) + rhi;
#pragma unroll
      for (int R = 0; R < 2; ++R)
#pragma unroll
        for (int G = 0; G < 4; ++G)
          redW[(R * 32 + rt) * 128 + G * 32 + cl] += acc[R][G][reg];
    }
    if (l < 32) { denW[cl] += den0; denW[32 + cl] += den1; }
  }
  __syncthreads();

  {
    f32x4* pn4 = (f32x4*)(pnum + (size_t)jc * N * F + (size_t)r0 * 128);
    const f32x4* rA = (const f32x4*)redA;
    const f32x4* rB = (const f32x4*)redB;
#pragma unroll
    for (int q = 0; q < 8; ++q)
      pn4[q * 256 + tid] = rA[q * 256 + tid] + rB[q * 256 + tid];
    if (tid < 64) pden[(size_t)jc * N + r0 + tid] = denA[tid] + denB[tid];
  }
}

// ---------------------------------------------------------------------------
// Kernel C: combine the JC j-chunk partials, normalize, ELU, store fp32.
// ---------------------------------------------------------------------------
__global__ __launch_bounds__(256) void k_final(
    const float* __restrict__ pnum, const float* __restrict__ pden,
    float* __restrict__ out)
{
  const int g = blockIdx.x * 256 + threadIdx.x;       // float4 index
  const int row = g >> 5;
  f32x4 n;
#pragma unroll
  for (int i = 0; i < 4; ++i) n[i] = 0.0f;
  float dd = 0.0f;
#pragma unroll
  for (int c = 0; c < JC; ++c) {
    n += ((const f32x4*)pnum)[(size_t)c * (N * F / 4) + g];
    dd += pden[(size_t)c * N + row];
  }
  f32x4 r = n * (1.0f / dd);
#pragma unroll
  for (int i = 0; i < 4; ++i) {
    float x = r[i];
    r[i] = x > 0.0f ? x : (__builtin_amdgcn_exp2f(x * 1.44269504f) - 1.0f);
  }
  ((f32x4*)out)[g] = r;
}

extern "C" void kernel_launch(void* const* d_in, const int* in_sizes, int n_in,
                              void* d_out, int out_size, void* d_ws, size_t ws_size,
                              hipStream_t stream)
{
  const float* h   = (const float*)d_in[0];
  const float* pos = (const float*)d_in[1];
  const float* W   = (const float*)d_in[2];
  const float* a   = (const float*)d_in[3];
  float* out = (float*)d_out;

  char* ws = (char*)d_ws;
  unsigned short* WhTf = (unsigned short*)ws;                // 2 MiB, tiled bf16
  float* cArr = (float*)(ws + (size_t)2 * 1024 * 1024);      // N floats
  float* dArr = cArr + N;                                    // N floats
  float* pden = dArr + N;                                    // JC*N floats
  float* pnum = pden + (size_t)JC * N;                       // JC*N*F floats (16 MiB)

  hipLaunchKernelGGL(k_gemm_cd, dim3(512), dim3(256), 0, stream,
                     h, pos, W, a, WhTf, cArr, dArr);
  hipLaunchKernelGGL(k_flash, dim3(128 * JC), dim3(256), 0, stream,
                     WhTf, cArr, dArr, pnum, pden);
  hipLaunchKernelGGL(k_final, dim3((N * F / 4) / 256), dim3(256), 0, stream,
                     pnum, pden, out);
}

// Round 4
// 111.102 us; speedup vs baseline: 1.2645x; 1.0382x over previous
//
#include <hip/hip_runtime.h>
#include <hip/hip_bf16.h>

#define N 8192
#define F 128
#define JC 8
#define JSLICE (N / JC)          // 1024

typedef __attribute__((ext_vector_type(4)))  float f32x4;
typedef __attribute__((ext_vector_type(16))) float f32x16;
typedef __attribute__((ext_vector_type(8)))  short short8;

static __device__ __forceinline__ short bf16bits(float x) {
  __hip_bfloat16 b = __float2bfloat16(x);   // RNE, native cvt
  return *reinterpret_cast<short*>(&b);
}

// ---------------------------------------------------------------------------
// Kernel A: Wh = h @ W (fp32), fused c[i] = Wh[i].a2 + p.a3, d[i] = Wh[i].a1 - p.a3,
// plus WhTf: fragment-tiled bf16 layout WhTf[(j/16)][col][j%16] so k_flash's
// B-frag loads are fully coalesced 1 KiB wave-transactions.
// 512 blocks x 256 threads, 16 rows/block (W staged in 64 KiB LDS).
// ---------------------------------------------------------------------------
__global__ __launch_bounds__(256) void k_gemm_cd(
    const float* __restrict__ h, const float* __restrict__ pos,
    const float* __restrict__ W, const float* __restrict__ a,
    unsigned short* __restrict__ WhTf, float* __restrict__ cArr,
    float* __restrict__ dArr)
{
  __shared__ float Ws[128 * 128];          // 64 KiB, reused as transpose buffer
  const int tid = threadIdx.x;
  const int r0  = blockIdx.x * 16;

  {
    f32x4* Ws4 = (f32x4*)Ws;
    const f32x4* Wg4 = (const f32x4*)W;
#pragma unroll
    for (int q = 0; q < 16; ++q) Ws4[q * 256 + tid] = Wg4[q * 256 + tid];
  }
  __syncthreads();

  const int rg  = tid >> 5;    // 0..7 -> rows rg*2, rg*2+1
  const int c32 = tid & 31;    // cols c32*4 .. c32*4+3

  f32x4 acc0, acc1;
#pragma unroll
  for (int i = 0; i < 4; ++i) { acc0[i] = 0.0f; acc1[i] = 0.0f; }

  const f32x4* h40 = (const f32x4*)(h + (size_t)(r0 + rg * 2) * 128);
  const f32x4* h41 = (const f32x4*)(h + (size_t)(r0 + rg * 2 + 1) * 128);
  const f32x4* Ws4 = (const f32x4*)Ws;

#pragma unroll 4
  for (int k4 = 0; k4 < 32; ++k4) {
    f32x4 hv0 = h40[k4];
    f32x4 hv1 = h41[k4];
#pragma unroll
    for (int e = 0; e < 4; ++e) {
      f32x4 w = Ws4[(k4 * 4 + e) * 32 + c32];
      acc0 += hv0[e] * w;
      acc1 += hv1[e] * w;
    }
  }

  // fused row dots: s1 = Wh.a1 (j-side), s2 = Wh.a2 (i-side)
  f32x4 a1v = *(const f32x4*)(a + c32 * 4);
  f32x4 a2v = *(const f32x4*)(a + 128 + c32 * 4);
#pragma unroll
  for (int rr = 0; rr < 2; ++rr) {
    f32x4 accR = rr ? acc1 : acc0;
    f32x4 t1 = accR * a1v;
    f32x4 t2 = accR * a2v;
    float s1 = t1[0] + t1[1] + t1[2] + t1[3];
    float s2 = t2[0] + t2[1] + t2[2] + t2[3];
#pragma unroll
    for (int m = 1; m < 32; m <<= 1) {
      s1 += __shfl_xor(s1, m);
      s2 += __shfl_xor(s2, m);
    }
    if (c32 == 0) {
      const int row = r0 + rg * 2 + rr;
      float pa = pos[row * 3 + 0] * a[256] + pos[row * 3 + 1] * a[257] +
                 pos[row * 3 + 2] * a[258];
      cArr[row] = s2 + pa;
      dArr[row] = s1 - pa;
    }
  }

  // transpose via LDS (reuse Ws), write bf16 fragment-tiled WhTf
  __syncthreads();
  float* tmp = Ws;             // [16][132] padded
  {
    const int base = (rg * 2) * 132 + c32 * 4;
    *(f32x4*)&tmp[base]       = acc0;
    *(f32x4*)&tmp[base + 132] = acc1;
  }
  __syncthreads();
  {
    const int col  = tid >> 1;         // 0..127
    const int half = tid & 1;          // local rows half*8 .. half*8+7
    short8 o;
#pragma unroll
    for (int rr = 0; rr < 8; ++rr)
      o[rr] = bf16bits(tmp[(half * 8 + rr) * 132 + col]);
    *(short8*)(WhTf + (size_t)(r0 >> 4) * 2048 + col * 16 + half * 8) = o;
  }
}

// ---------------------------------------------------------------------------
// Kernel B: flash attention, scores bounded -> plain partial sums.
// Grid 1024: jc = bid>>7 (j-chunk of 1024), rowblock = bid&127 (64 rows).
// 4 waves: (w&1) = 32-row tile, (w>>1) = 512-j half.  acc[4] = 64 AGPR
// -> ~116 total regs -> 4 waves/SIMD; LDS 36.5 KB -> 4 blocks/CU.
// Per iter (16 j): 8 exps/lane -> 1 A-frag, 4 coalesced 1KB B-loads, 4 MFMAs.
// Cross-wave reduce: pairs (0,2),(1,3) via one 32 KiB LDS buffer.
// ---------------------------------------------------------------------------
__global__ __launch_bounds__(256, 4) void k_flash(
    const unsigned short* __restrict__ WhTf, const float* __restrict__ cArr,
    const float* __restrict__ dArr, float* __restrict__ pnum,
    float* __restrict__ pden)
{
  __shared__ __align__(16) float dS[JSLICE];   // 4 KiB
  __shared__ float red[64 * 128];              // 32 KiB
  __shared__ float denS[64];

  const int tid = threadIdx.x;
  const int jc  = blockIdx.x >> 7;
  const int r0  = (blockIdx.x & 127) * 64;

  {
    const f32x4* s4 = (const f32x4*)(dArr + (size_t)jc * JSLICE);
    ((f32x4*)dS)[tid] = s4[tid];
  }
  __syncthreads();

  const int w  = tid >> 6;
  const int l  = tid & 63;
  const int cl = l & 31;
  const int kh = l >> 5;
  const int rt = w & 1;                    // row tile (32 rows)
  const int jw = (w >> 1) * (JSLICE / 2);  // 512-j half
  const float L2E = 1.44269504f;
  const float ci = cArr[r0 + rt * 32 + cl] * L2E;

  f32x16 acc0, acc1, acc2, acc3;
#pragma unroll
  for (int i = 0; i < 16; ++i) { acc0[i] = 0; acc1[i] = 0; acc2[i] = 0; acc3[i] = 0; }
  float den = 0.0f;

  const unsigned short* bPtr =
      WhTf + ((size_t)(jc * JSLICE + jw) >> 4) * 2048 + cl * 16 + kh * 8;
  const float* dPtr = dS + jw + kh * 8;

  // prologue: first B fragments
  short8 b0 = *(const short8*)(bPtr);
  short8 b1 = *(const short8*)(bPtr + 512);
  short8 b2 = *(const short8*)(bPtr + 1024);
  short8 b3 = *(const short8*)(bPtr + 1536);
  bPtr += 2048;

  const int iters = (JSLICE / 2) / 16;     // 32
  for (int kk = 0; kk < iters; ++kk) {
    // prefetch next iteration's B (last-iter overrun stays inside d_ws)
    short8 n0 = *(const short8*)(bPtr);
    short8 n1 = *(const short8*)(bPtr + 512);
    short8 n2 = *(const short8*)(bPtr + 1024);
    short8 n3 = *(const short8*)(bPtr + 1536);

    f32x4 dj0 = *(const f32x4*)(dPtr);
    f32x4 dj1 = *(const f32x4*)(dPtr + 4);
    short8 af;
#pragma unroll
    for (int e = 0; e < 8; ++e) {
      float dj = (e < 4) ? dj0[e] : dj1[e - 4];
      float u = __builtin_fmaf(dj, L2E, ci);   // (c_i + d_j)*log2e
      u = fmaxf(u, 0.2f * u);                  // leaky_relu in log2 domain
      float pv = __builtin_amdgcn_exp2f(u);
      den += pv;
      af[e] = bf16bits(pv);
    }

    acc0 = __builtin_amdgcn_mfma_f32_32x32x16_bf16(af, b0, acc0, 0, 0, 0);
    acc1 = __builtin_amdgcn_mfma_f32_32x32x16_bf16(af, b1, acc1, 0, 0, 0);
    acc2 = __builtin_amdgcn_mfma_f32_32x32x16_bf16(af, b2, acc2, 0, 0, 0);
    acc3 = __builtin_amdgcn_mfma_f32_32x32x16_bf16(af, b3, acc3, 0, 0, 0);

    b0 = n0; b1 = n1; b2 = n2; b3 = n3;
    bPtr += 2048; dPtr += 16;
  }

  // combine kh halves of each row's denominator
  den += __shfl_xor(den, 32);

  // cross-wave reduce: pairs (0,2) rows 0-31, (1,3) rows 32-63
  const int rtb = 32 * rt;
  const int rhi = 4 * kh;
  if (w < 2) {
#pragma unroll
    for (int reg = 0; reg < 16; ++reg) {
      const int rr = (reg & 3) + 8 * (reg >> 2) + rhi;
      red[(rtb + rr) * 128 +  0 + cl] = acc0[reg];
      red[(rtb + rr) * 128 + 32 + cl] = acc1[reg];
      red[(rtb + rr) * 128 + 64 + cl] = acc2[reg];
      red[(rtb + rr) * 128 + 96 + cl] = acc3[reg];
    }
    if (l < 32) denS[rtb + l] = den;
  }
  __syncthreads();
  if (w >= 2) {
#pragma unroll
    for (int reg = 0; reg < 16; ++reg) {
      const int rr = (reg & 3) + 8 * (reg >> 2) + rhi;
      red[(rtb + rr) * 128 +  0 + cl] += acc0[reg];
      red[(rtb + rr) * 128 + 32 + cl] += acc1[reg];
      red[(rtb + rr) * 128 + 64 + cl] += acc2[reg];
      red[(rtb + rr) * 128 + 96 + cl] += acc3[reg];
    }
    if (l < 32) denS[rtb + l] += den;
  }
  __syncthreads();

  {
    f32x4* pn4 = (f32x4*)(pnum + (size_t)jc * N * F + (size_t)r0 * 128);
    const f32x4* r4 = (const f32x4*)red;
#pragma unroll
    for (int q = 0; q < 8; ++q) pn4[q * 256 + tid] = r4[q * 256 + tid];
    if (tid < 64) pden[(size_t)jc * N + r0 + tid] = denS[tid];
  }
}

// ---------------------------------------------------------------------------
// Kernel C: combine the JC j-chunk partials, normalize, ELU, store fp32.
// ---------------------------------------------------------------------------
__global__ __launch_bounds__(256) void k_final(
    const float* __restrict__ pnum, const float* __restrict__ pden,
    float* __restrict__ out)
{
  const int g = blockIdx.x * 256 + threadIdx.x;       // float4 index
  const int row = g >> 5;
  f32x4 n;
#pragma unroll
  for (int i = 0; i < 4; ++i) n[i] = 0.0f;
  float dd = 0.0f;
#pragma unroll
  for (int c = 0; c < JC; ++c) {
    n += ((const f32x4*)pnum)[(size_t)c * (N * F / 4) + g];
    dd += pden[(size_t)c * N + row];
  }
  f32x4 r = n * (1.0f / dd);
#pragma unroll
  for (int i = 0; i < 4; ++i) {
    float x = r[i];
    r[i] = x > 0.0f ? x : (__builtin_amdgcn_exp2f(x * 1.44269504f) - 1.0f);
  }
  ((f32x4*)out)[g] = r;
}

extern "C" void kernel_launch(void* const* d_in, const int* in_sizes, int n_in,
                              void* d_out, int out_size, void* d_ws, size_t ws_size,
                              hipStream_t stream)
{
  const float* h   = (const float*)d_in[0];
  const float* pos = (const float*)d_in[1];
  const float* W   = (const float*)d_in[2];
  const float* a   = (const float*)d_in[3];
  float* out = (float*)d_out;

  char* ws = (char*)d_ws;
  unsigned short* WhTf = (unsigned short*)ws;                // 2 MiB, tiled bf16
  float* cArr = (float*)(ws + (size_t)2 * 1024 * 1024);      // N floats
  float* dArr = cArr + N;                                    // N floats
  float* pden = dArr + N;                                    // JC*N floats
  float* pnum = pden + (size_t)JC * N;                       // JC*N*F floats (32 MiB)

  hipLaunchKernelGGL(k_gemm_cd, dim3(512), dim3(256), 0, stream,
                     h, pos, W, a, WhTf, cArr, dArr);
  hipLaunchKernelGGL(k_flash, dim3(128 * JC), dim3(256), 0, stream,
                     WhTf, cArr, dArr, pnum, pden);
  hipLaunchKernelGGL(k_final, dim3((N * F / 4) / 256), dim3(256), 0, stream,
                     pnum, pden, out);
}

// Round 5
// 109.625 us; speedup vs baseline: 1.2816x; 1.0135x over previous
//
#include <hip/hip_runtime.h>
#include <hip/hip_bf16.h>

#define N 8192
#define F 128
#define JC 16
#define JSLICE (N / JC)          // 512
#define CHUNKJ 32                // j per staged chunk (2 k-steps)
#define NSC (JSLICE / CHUNKJ)    // 16 chunks

typedef __attribute__((ext_vector_type(4)))  float f32x4;
typedef __attribute__((ext_vector_type(16))) float f32x16;
typedef __attribute__((ext_vector_type(8)))  short short8;

static __device__ __forceinline__ short bf16bits(float x) {
  __hip_bfloat16 b = __float2bfloat16(x);   // RNE, native cvt
  return *reinterpret_cast<short*>(&b);
}

static __device__ __forceinline__ void gload_lds16(const void* g, void* lds) {
  __builtin_amdgcn_global_load_lds(
      (const __attribute__((address_space(1))) void*)g,
      (__attribute__((address_space(3))) void*)lds, 16, 0, 0);
}

// ---------------------------------------------------------------------------
// Kernel A: Wh = h @ W (fp32), fused c[i] = Wh[i].a2 + p.a3, d[i] = Wh[i].a1 - p.a3,
// plus WhTf: fragment-tiled bf16 layout WhTf[(j/16)][col][j%16] so B-frag loads
// are fully coalesced. 512 blocks x 256 threads, 16 rows/block.
// ---------------------------------------------------------------------------
__global__ __launch_bounds__(256) void k_gemm_cd(
    const float* __restrict__ h, const float* __restrict__ pos,
    const float* __restrict__ W, const float* __restrict__ a,
    unsigned short* __restrict__ WhTf, float* __restrict__ cArr,
    float* __restrict__ dArr)
{
  __shared__ float Ws[128 * 128];          // 64 KiB, reused as transpose buffer
  const int tid = threadIdx.x;
  const int r0  = blockIdx.x * 16;

  {
    f32x4* Ws4 = (f32x4*)Ws;
    const f32x4* Wg4 = (const f32x4*)W;
#pragma unroll
    for (int q = 0; q < 16; ++q) Ws4[q * 256 + tid] = Wg4[q * 256 + tid];
  }
  __syncthreads();

  const int rg  = tid >> 5;    // 0..7 -> rows rg*2, rg*2+1
  const int c32 = tid & 31;    // cols c32*4 .. c32*4+3

  f32x4 acc0, acc1;
#pragma unroll
  for (int i = 0; i < 4; ++i) { acc0[i] = 0.0f; acc1[i] = 0.0f; }

  const f32x4* h40 = (const f32x4*)(h + (size_t)(r0 + rg * 2) * 128);
  const f32x4* h41 = (const f32x4*)(h + (size_t)(r0 + rg * 2 + 1) * 128);
  const f32x4* Ws4 = (const f32x4*)Ws;

#pragma unroll 4
  for (int k4 = 0; k4 < 32; ++k4) {
    f32x4 hv0 = h40[k4];
    f32x4 hv1 = h41[k4];
#pragma unroll
    for (int e = 0; e < 4; ++e) {
      f32x4 w = Ws4[(k4 * 4 + e) * 32 + c32];
      acc0 += hv0[e] * w;
      acc1 += hv1[e] * w;
    }
  }

  // fused row dots
  f32x4 a1v = *(const f32x4*)(a + c32 * 4);
  f32x4 a2v = *(const f32x4*)(a + 128 + c32 * 4);
#pragma unroll
  for (int rr = 0; rr < 2; ++rr) {
    f32x4 accR = rr ? acc1 : acc0;
    f32x4 t1 = accR * a1v;
    f32x4 t2 = accR * a2v;
    float s1 = t1[0] + t1[1] + t1[2] + t1[3];
    float s2 = t2[0] + t2[1] + t2[2] + t2[3];
#pragma unroll
    for (int m = 1; m < 32; m <<= 1) {
      s1 += __shfl_xor(s1, m);
      s2 += __shfl_xor(s2, m);
    }
    if (c32 == 0) {
      const int row = r0 + rg * 2 + rr;
      float pa = pos[row * 3 + 0] * a[256] + pos[row * 3 + 1] * a[257] +
                 pos[row * 3 + 2] * a[258];
      cArr[row] = s2 + pa;
      dArr[row] = s1 - pa;
    }
  }

  // transpose via LDS, write bf16 fragment-tiled WhTf
  __syncthreads();
  float* tmp = Ws;             // [16][132] padded
  {
    const int base = (rg * 2) * 132 + c32 * 4;
    *(f32x4*)&tmp[base]       = acc0;
    *(f32x4*)&tmp[base + 132] = acc1;
  }
  __syncthreads();
  {
    const int col  = tid >> 1;
    const int half = tid & 1;
    short8 o;
#pragma unroll
    for (int rr = 0; rr < 8; ++rr)
      o[rr] = bf16bits(tmp[(half * 8 + rr) * 132 + col]);
    *(short8*)(WhTf + (size_t)(r0 >> 4) * 2048 + col * 16 + half * 8) = o;
  }
}

// ---------------------------------------------------------------------------
// Kernel B: flash attention, scores bounded -> plain partial sums.
// Grid 1024: rb = bid & 63 (128 rows), jc = bid >> 6 (512-j chunk).
// 4 waves x one 32-row MFMA tile each; all waves share one j-stream.
// B staged via global_load_lds into a 2 x 8 KiB double buffer (32 j per chunk);
// each wave owns disjoint rows -> no cross-wave reduce; direct AGPR->pnum store.
// ---------------------------------------------------------------------------
__global__ __launch_bounds__(256, 4) void k_flash(
    const unsigned short* __restrict__ WhTf, const float* __restrict__ cArr,
    const float* __restrict__ dArr, float* __restrict__ pnum,
    float* __restrict__ pden)
{
  __shared__ __align__(16) unsigned short bufS[2][CHUNKJ * 128];  // 2 x 8 KiB
  __shared__ __align__(16) float dS[JSLICE];                      // 2 KiB

  const int tid = threadIdx.x;
  const int rb  = blockIdx.x & 63;
  const int jc  = blockIdx.x >> 6;
  const int r0  = rb * 128;

  const int w  = tid >> 6;
  const int l  = tid & 63;
  const int cl = l & 31;
  const int kh = l >> 5;

  // chunk source base (shorts): chunk sc covers k-steps jc*32 + sc*2 .. +1
  const unsigned short* gBase = WhTf + ((size_t)jc * 32) * 2048;

  // stage chunk 0 + dS
  {
    const char* gs = (const char*)gBase + (w * 2) * 1024 + l * 16;
    char* ld = (char*)&bufS[0][0] + (w * 2) * 1024;
    gload_lds16(gs, ld);
    gload_lds16(gs + 1024, ld + 1024);
    if (tid < JSLICE / 4)
      ((f32x4*)dS)[tid] = ((const f32x4*)(dArr + (size_t)jc * JSLICE))[tid];
  }
  __syncthreads();

  const float L2E = 1.44269504f;
  const float ci = cArr[r0 + w * 32 + cl] * L2E;

  f32x16 acc0, acc1, acc2, acc3;
#pragma unroll
  for (int i = 0; i < 16; ++i) { acc0[i] = 0; acc1[i] = 0; acc2[i] = 0; acc3[i] = 0; }
  float denA = 0.0f, denB = 0.0f;

  for (int sc = 0; sc < NSC; ++sc) {
    const int cur = sc & 1;
    // stage next chunk into the other buffer (async, drains at the barrier)
    if (sc + 1 < NSC) {
      const char* gs = (const char*)gBase + (size_t)(sc + 1) * (CHUNKJ * 128 * 2)
                     + (w * 2) * 1024 + l * 16;
      char* ld = (char*)&bufS[cur ^ 1][0] + (w * 2) * 1024;
      gload_lds16(gs, ld);
      gload_lds16(gs + 1024, ld + 1024);
    }

#pragma unroll
    for (int ks = 0; ks < 2; ++ks) {
      const unsigned short* bs = &bufS[cur][ks * 2048];
      short8 b0 = *(const short8*)(bs +    0 + cl * 16 + kh * 8);
      short8 b1 = *(const short8*)(bs +  512 + cl * 16 + kh * 8);
      short8 b2 = *(const short8*)(bs + 1024 + cl * 16 + kh * 8);
      short8 b3 = *(const short8*)(bs + 1536 + cl * 16 + kh * 8);

      const int jo = sc * CHUNKJ + ks * 16 + kh * 8;
      f32x4 dj0 = *(const f32x4*)&dS[jo];
      f32x4 dj1 = *(const f32x4*)&dS[jo + 4];

      short8 af;
#pragma unroll
      for (int e = 0; e < 8; ++e) {
        float dj = (e < 4) ? dj0[e] : dj1[e - 4];
        float u = __builtin_fmaf(dj, L2E, ci);   // (c_i + d_j)*log2e
        u = fmaxf(u, 0.2f * u);                  // leaky_relu in log2 domain
        float pv = __builtin_amdgcn_exp2f(u);
        if (e & 1) denB += pv; else denA += pv;
        af[e] = bf16bits(pv);
      }

      acc0 = __builtin_amdgcn_mfma_f32_32x32x16_bf16(af, b0, acc0, 0, 0, 0);
      acc1 = __builtin_amdgcn_mfma_f32_32x32x16_bf16(af, b1, acc1, 0, 0, 0);
      acc2 = __builtin_amdgcn_mfma_f32_32x32x16_bf16(af, b2, acc2, 0, 0, 0);
      acc3 = __builtin_amdgcn_mfma_f32_32x32x16_bf16(af, b3, acc3, 0, 0, 0);
    }
    __syncthreads();
  }

  float den = denA + denB;
  den += __shfl_xor(den, 32);

  // direct per-wave epilogue: 32 rows x 128 cols from AGPRs
  {
    float* base = pnum + (size_t)jc * N * F + (size_t)(r0 + w * 32) * 128;
#pragma unroll
    for (int reg = 0; reg < 16; ++reg) {
      const int row = (reg & 3) + 8 * (reg >> 2) + 4 * kh;
      float* rp = base + row * 128 + cl;
      rp[0]  = acc0[reg];
      rp[32] = acc1[reg];
      rp[64] = acc2[reg];
      rp[96] = acc3[reg];
    }
    if (l < 32) pden[(size_t)jc * N + r0 + w * 32 + l] = den;
  }
}

// ---------------------------------------------------------------------------
// Kernel C: combine the JC j-chunk partials, normalize, ELU, store fp32.
// ---------------------------------------------------------------------------
__global__ __launch_bounds__(256) void k_final(
    const float* __restrict__ pnum, const float* __restrict__ pden,
    float* __restrict__ out)
{
  const int g = blockIdx.x * 256 + threadIdx.x;       // float4 index
  const int row = g >> 5;
  f32x4 n;
#pragma unroll
  for (int i = 0; i < 4; ++i) n[i] = 0.0f;
  float dd = 0.0f;
#pragma unroll
  for (int c = 0; c < JC; ++c) {
    n += ((const f32x4*)pnum)[(size_t)c * (N * F / 4) + g];
    dd += pden[(size_t)c * N + row];
  }
  f32x4 r = n * (1.0f / dd);
#pragma unroll
  for (int i = 0; i < 4; ++i) {
    float x = r[i];
    r[i] = x > 0.0f ? x : (__builtin_amdgcn_exp2f(x * 1.44269504f) - 1.0f);
  }
  ((f32x4*)out)[g] = r;
}

extern "C" void kernel_launch(void* const* d_in, const int* in_sizes, int n_in,
                              void* d_out, int out_size, void* d_ws, size_t ws_size,
                              hipStream_t stream)
{
  const float* h   = (const float*)d_in[0];
  const float* pos = (const float*)d_in[1];
  const float* W   = (const float*)d_in[2];
  const float* a   = (const float*)d_in[3];
  float* out = (float*)d_out;

  char* ws = (char*)d_ws;
  unsigned short* WhTf = (unsigned short*)ws;                // 2 MiB, tiled bf16
  float* cArr = (float*)(ws + (size_t)2 * 1024 * 1024);      // N floats
  float* dArr = cArr + N;                                    // N floats
  float* pden = dArr + N;                                    // JC*N floats
  float* pnum = pden + (size_t)JC * N;                       // JC*N*F floats (64 MiB)

  hipLaunchKernelGGL(k_gemm_cd, dim3(512), dim3(256), 0, stream,
                     h, pos, W, a, WhTf, cArr, dArr);
  hipLaunchKernelGGL(k_flash, dim3(64 * JC), dim3(256), 0, stream,
                     WhTf, cArr, dArr, pnum, pden);
  hipLaunchKernelGGL(k_final, dim3((N * F / 4) / 256), dim3(256), 0, stream,
                     pnum, pden, out);
}